// Round 1
// baseline (315.728 us; speedup 1.0000x reference)
//
#include <hip/hip_runtime.h>
#include <math.h>

#define NP 50000
#define CH 64
#define KMAX 64
#define KNN 16
#define NB 25
#define PTS (NP / NB)          // 2000
#define EPSF 1e-16f

// ---------------------------------------------------------------------------
// Kernel 1: QKV projections.  9 GEMMs of [N,64] @ [64,64].
// block = (64 lanes = out-channel, 4 waves). Each wave processes 64 rows.
// W column for this lane lives in 64 VGPRs; x row is wave-uniform (scalar loads).
// mat 0..2 -> Q (Wq), 3..5 -> K (Wk), 6..8 -> V (Wv); out at ws + mat*N*C.
// ---------------------------------------------------------------------------
__global__ __launch_bounds__(256) void qkv_kernel(
    const float* __restrict__ x,
    const float* __restrict__ Wv,
    const float* __restrict__ Wq,
    const float* __restrict__ Wk,
    float* __restrict__ ws) {
  const int lane = threadIdx.x;          // out channel
  const int wave = threadIdx.y;          // 0..3
  const int mat  = blockIdx.y;           // 0..8

  const float* W;
  int d;
  if (mat < 3)      { W = Wq; d = mat;     }
  else if (mat < 6) { W = Wk; d = mat - 3; }
  else              { W = Wv; d = mat - 6; }
  const float* Wd = W + d * (CH * CH);

  float wreg[CH];
#pragma unroll
  for (int ic = 0; ic < CH; ++ic) wreg[ic] = Wd[ic * CH + lane];

  float* outBase = ws + (size_t)mat * NP * CH;
  const int rowBase = blockIdx.x * 256 + wave * 64;

  for (int r = 0; r < 64; ++r) {
    int row = __builtin_amdgcn_readfirstlane(rowBase + r);
    if (row >= NP) break;                // wave-uniform exit
    const float* xr = x + (size_t)row * CH;
    float acc = 0.f;
#pragma unroll
    for (int ic = 0; ic < CH; ++ic) acc = fmaf(xr[ic], wreg[ic], acc);
    outBase[(size_t)row * CH + lane] = acc;
  }
}

// ---------------------------------------------------------------------------
// Kernel 2: per-cloud channel max pool.  grid = 25 blocks, block = (64,4).
// ---------------------------------------------------------------------------
__global__ __launch_bounds__(256) void pool_kernel(
    const float* __restrict__ x, float* __restrict__ pool) {
  const int lane = threadIdx.x;
  const int wave = threadIdx.y;
  const int b = blockIdx.x;
  const float* xb = x + (size_t)b * PTS * CH;

  float m0 = -INFINITY, m1 = -INFINITY, m2 = -INFINITY, m3 = -INFINITY;
  for (int r = wave * 4; r < PTS; r += 16) {   // 125 iters, 4 indep streams
    m0 = fmaxf(m0, xb[(size_t)(r + 0) * CH + lane]);
    m1 = fmaxf(m1, xb[(size_t)(r + 1) * CH + lane]);
    m2 = fmaxf(m2, xb[(size_t)(r + 2) * CH + lane]);
    m3 = fmaxf(m3, xb[(size_t)(r + 3) * CH + lane]);
  }
  float m = fmaxf(fmaxf(m0, m1), fmaxf(m2, m3));

  __shared__ float red[4][CH];
  red[wave][lane] = m;
  __syncthreads();
  if (wave == 0) {
    float v = fmaxf(fmaxf(red[0][lane], red[1][lane]),
                    fmaxf(red[2][lane], red[3][lane]));
    pool[b * CH + lane] = v;
  }
}

// ---------------------------------------------------------------------------
// Kernel 3: fused dilated point-transformer attention + branch max + pool max
// + residual.  One wave per node (lane = channel), 4 nodes per block.
// Register-resident two-pass softmax over the 16 edges of each dilation.
// ---------------------------------------------------------------------------
__global__ __launch_bounds__(256) void attn_kernel(
    const float* __restrict__ x,
    const float* __restrict__ pos,
    const float* __restrict__ Wp,
    const float* __restrict__ bp,
    const int*   __restrict__ edge_src,    // row 0 of edge_index, N*KMAX
    const int*   __restrict__ batch,
    const float* __restrict__ ws,          // Q|K|V
    const float* __restrict__ pool,
    float* __restrict__ out) {
  const int lane = threadIdx.x;            // channel
  const int wave = threadIdx.y;
  const int node = __builtin_amdgcn_readfirstlane(blockIdx.x * 4 + threadIdx.y);

  __shared__ int   sIdx[4][KMAX];
  __shared__ float sRel[4][3][KMAX];

  // prologue: lane l caches neighbor l's index and rel-pos (pos_i - pos_j)
  {
    int j = edge_src[(size_t)node * KMAX + lane];
    sIdx[wave][lane] = j;
    float px = pos[(size_t)node * 3 + 0];
    float py = pos[(size_t)node * 3 + 1];
    float pz = pos[(size_t)node * 3 + 2];
    sRel[wave][0][lane] = px - pos[(size_t)j * 3 + 0];
    sRel[wave][1][lane] = py - pos[(size_t)j * 3 + 1];
    sRel[wave][2][lane] = pz - pos[(size_t)j * 3 + 2];
  }
  __syncthreads();

  const float* Qb = ws;
  const float* Kb = ws + (size_t)3 * NP * CH;
  const float* Vb = ws + (size_t)6 * NP * CH;

  const float xi = x[(size_t)node * CH + lane];
  float res = 0.f;

#pragma unroll
  for (int dd = 0; dd < 3; ++dd) {
    const int dil = 1 << dd;               // 1, 2, 4
    const float q   = Qb[((size_t)dd * NP + node) * CH + lane];
    const float wp0 = Wp[dd * 192 + 0 * CH + lane];
    const float wp1 = Wp[dd * 192 + 1 * CH + lane];
    const float wp2 = Wp[dd * 192 + 2 * CH + lane];
    const float bpv = bp[dd * CH + lane];
    const float* Kd = Kb + (size_t)dd * NP * CH;
    const float* Vd = Vb + (size_t)dd * NP * CH;

    float a[KNN], vd[KNN];
    float m = -INFINITY;
#pragma unroll
    for (int e = 0; e < KNN; ++e) {
      const int p = e * dil;
      int jj = __builtin_amdgcn_readfirstlane(sIdx[wave][p]);
      float r0 = sRel[wave][0][p];
      float r1 = sRel[wave][1][p];
      float r2 = sRel[wave][2][p];
      float delta = fmaf(r0, wp0, fmaf(r1, wp1, fmaf(r2, wp2, bpv)));
      float kv = Kd[(size_t)jj * CH + lane];
      float vv = Vd[(size_t)jj * CH + lane];
      a[e]  = q - kv + delta;
      vd[e] = vv + delta;
      m = fmaxf(m, a[e]);
    }
    float s = 0.f, acc = 0.f;
#pragma unroll
    for (int e = 0; e < KNN; ++e) {
      float w = __expf(a[e] - m);
      s += w;
      acc = fmaf(w, vd[e], acc);
    }
    float r = acc / (s + EPSF);
    res = (dd == 0) ? r : fmaxf(res, r);
  }

  const int b = batch[node];
  res = fmaxf(res, pool[b * CH + lane]);
  out[(size_t)node * CH + lane] = res + xi;
}

// ---------------------------------------------------------------------------
extern "C" void kernel_launch(void* const* d_in, const int* in_sizes, int n_in,
                              void* d_out, int out_size, void* d_ws, size_t ws_size,
                              hipStream_t stream) {
  const float* x    = (const float*)d_in[0];
  const float* pos  = (const float*)d_in[1];
  const float* Wv   = (const float*)d_in[2];
  const float* Wq   = (const float*)d_in[3];
  const float* Wk   = (const float*)d_in[4];
  const float* Wp   = (const float*)d_in[5];
  const float* bp   = (const float*)d_in[6];
  const int*   ei   = (const int*)d_in[7];     // [2, N*KMAX]; row 0 = src
  const int*   batch = (const int*)d_in[8];
  float* out = (float*)d_out;

  float* ws   = (float*)d_ws;                  // 9*N*C floats for Q|K|V
  float* pool = ws + (size_t)9 * NP * CH;      // + 25*64 floats

  // 1) QKV projections
  {
    dim3 grid((NP + 255) / 256, 9);
    dim3 block(64, 4);
    hipLaunchKernelGGL(qkv_kernel, grid, block, 0, stream, x, Wv, Wq, Wk, ws);
  }
  // 2) per-cloud max pool (independent of 1, same stream)
  {
    dim3 grid(NB);
    dim3 block(64, 4);
    hipLaunchKernelGGL(pool_kernel, grid, block, 0, stream, x, pool);
  }
  // 3) fused attention + combine
  {
    dim3 grid(NP / 4);
    dim3 block(64, 4);
    hipLaunchKernelGGL(attn_kernel, grid, block, 0, stream,
                       x, pos, Wp, bp, ei, batch, ws, pool, out);
  }
}

// Round 2
// 233.518 us; speedup vs baseline: 1.3521x; 1.3521x over previous
//
#include <hip/hip_runtime.h>
#include <math.h>

#define NP 50000
#define CH 64
#define KMAX 64
#define KNN 16
#define NB 25
#define PTS (NP / NB)          // 2000
#define EPSF 1e-16f
#define NTILES ((NP + 15) / 16)   // 3125 exact

typedef __attribute__((ext_vector_type(8))) short short8;
typedef __attribute__((ext_vector_type(4))) float float4v;

__device__ __forceinline__ ushort f2b(float f) {
  unsigned u = __float_as_uint(f);
  unsigned r = (u + 0x7FFFu + ((u >> 16) & 1u)) >> 16;
  return (ushort)r;
}
__device__ __forceinline__ float b2f(ushort h) {
  return __uint_as_float(((unsigned)h) << 16);
}

// ws layout (bytes):
//   qkv  : 9 * NP * CH * 2                     (bf16)  mats 0-2=Q, 3-5=K, 6-8=V
//   x_bf : NP * CH * 2                         (bf16)
//   wpack: 9*4*2*64*8 * 2 = 73728              (bf16, A-frag layout)
//   pool : NB * CH * 4                         (fp32)
#define QKV_BYTES   ((size_t)9 * NP * CH * 2)
#define XBF_BYTES   ((size_t)NP * CH * 2)
#define WPACK_ELEMS (9 * 4 * 2 * 64 * 8)

// ---------------------------------------------------------------------------
// Kernel 0: convert x -> bf16 (float4-vectorized) and pack W into A-frag
// layout: wpack[((mat*4+mtile)*2+kstep)*512 + lane*8 + j] = W[mat][ic][oc]
//   oc = mtile*16 + (lane&15), ic = kstep*32 + ((lane>>4)&3)*8 + j
// ---------------------------------------------------------------------------
#define XV (NP * CH / 4)   // 800000 float4 groups
__global__ __launch_bounds__(256) void convert_kernel(
    const float* __restrict__ x,
    const float* __restrict__ Wv,
    const float* __restrict__ Wq,
    const float* __restrict__ Wk,
    ushort* __restrict__ x_bf,
    ushort* __restrict__ wpack) {
  const int gid = blockIdx.x * 256 + threadIdx.x;
  if (gid < XV) {
    const float4* xv = (const float4*)x;
    float4 v = xv[gid];
    ushort4 o;
    o.x = f2b(v.x); o.y = f2b(v.y); o.z = f2b(v.z); o.w = f2b(v.w);
    *(ushort4*)(x_bf + (size_t)gid * 4) = o;
  } else {
    int pid = gid - XV;
    if (pid < WPACK_ELEMS) {
      int j     = pid & 7;
      int lane  = (pid >> 3) & 63;
      int kstep = (pid >> 9) & 1;
      int mtile = (pid >> 10) & 3;
      int mat   = pid >> 12;
      const float* W;
      int d;
      if (mat < 3)      { W = Wq; d = mat;     }
      else if (mat < 6) { W = Wk; d = mat - 3; }
      else              { W = Wv; d = mat - 6; }
      int oc = mtile * 16 + (lane & 15);
      int ic = kstep * 32 + ((lane >> 4) & 3) * 8 + j;
      wpack[pid] = f2b(W[d * CH * CH + ic * CH + oc]);
    }
  }
}

// ---------------------------------------------------------------------------
// Kernel 1: QKV via MFMA 16x16x32 bf16, transposed formulation.
//   A = W^T  (M=oc, K=ic)   from wpack (one dwordx4 per frag per lane)
//   B = x^T  (K=ic, N=node) lane loads 16B contiguous from x_bf row
//   D lane holds node=lane&15 (col), oc=mtile*16+(lane>>4)*4+reg (row)
// grid: (ceil(NTILES/16), 9), block (64,4); each wave: 4 node-tiles.
// ---------------------------------------------------------------------------
#define TPW 4
__global__ __launch_bounds__(256) void qkv_mfma(
    const ushort* __restrict__ x_bf,
    const ushort* __restrict__ wpack,
    ushort* __restrict__ qkv) {
  const int lane = threadIdx.x;
  const int wave = threadIdx.y;
  const int mat  = blockIdx.y;

  // Resident A-frags: [mtile][kstep]
  short8 afrag[4][2];
#pragma unroll
  for (int mt = 0; mt < 4; ++mt)
#pragma unroll
    for (int ks = 0; ks < 2; ++ks)
      afrag[mt][ks] = *(const short8*)(wpack +
          ((((size_t)mat * 4 + mt) * 2 + ks) * 64 + lane) * 8);

  ushort* outM = qkv + (size_t)mat * NP * CH;
  const int kbase = (lane >> 4) * 8;
  const int tile0 = (blockIdx.x * 4 + wave) * TPW;

#pragma unroll
  for (int t = 0; t < TPW; ++t) {
    int tile = tile0 + t;
    if (tile >= NTILES) break;           // wave-uniform
    int myNode = tile * 16 + (lane & 15);
    const ushort* xr = x_bf + (size_t)myNode * CH;
    short8 b0 = *(const short8*)(xr + kbase);
    short8 b1 = *(const short8*)(xr + 32 + kbase);
#pragma unroll
    for (int mt = 0; mt < 4; ++mt) {
      float4v acc = {0.f, 0.f, 0.f, 0.f};
      acc = __builtin_amdgcn_mfma_f32_16x16x32_bf16(afrag[mt][0], b0, acc, 0, 0, 0);
      acc = __builtin_amdgcn_mfma_f32_16x16x32_bf16(afrag[mt][1], b1, acc, 0, 0, 0);
      int oc = mt * 16 + (lane >> 4) * 4;
      uint2 o;
      o.x = (unsigned)f2b(acc[0]) | ((unsigned)f2b(acc[1]) << 16);
      o.y = (unsigned)f2b(acc[2]) | ((unsigned)f2b(acc[3]) << 16);
      *(uint2*)(outM + (size_t)myNode * CH + oc) = o;
    }
  }
}

// ---------------------------------------------------------------------------
// Kernel 2: per-cloud channel max pool (unchanged, exact fp32).
// ---------------------------------------------------------------------------
__global__ __launch_bounds__(256) void pool_kernel(
    const float* __restrict__ x, float* __restrict__ pool) {
  const int lane = threadIdx.x;
  const int wave = threadIdx.y;
  const int b = blockIdx.x;
  const float* xb = x + (size_t)b * PTS * CH;

  float m0 = -INFINITY, m1 = -INFINITY, m2 = -INFINITY, m3 = -INFINITY;
  for (int r = wave * 4; r < PTS; r += 16) {
    m0 = fmaxf(m0, xb[(size_t)(r + 0) * CH + lane]);
    m1 = fmaxf(m1, xb[(size_t)(r + 1) * CH + lane]);
    m2 = fmaxf(m2, xb[(size_t)(r + 2) * CH + lane]);
    m3 = fmaxf(m3, xb[(size_t)(r + 3) * CH + lane]);
  }
  float m = fmaxf(fmaxf(m0, m1), fmaxf(m2, m3));

  __shared__ float red[4][CH];
  red[wave][lane] = m;
  __syncthreads();
  if (wave == 0) {
    float v = fmaxf(fmaxf(red[0][lane], red[1][lane]),
                    fmaxf(red[2][lane], red[3][lane]));
    pool[b * CH + lane] = v;
  }
}

// ---------------------------------------------------------------------------
// Kernel 3: fused attention (bf16 Q/K/V gathers) + branch max + pool + resid.
// ---------------------------------------------------------------------------
__global__ __launch_bounds__(256) void attn_kernel(
    const float* __restrict__ x,
    const float* __restrict__ pos,
    const float* __restrict__ Wp,
    const float* __restrict__ bp,
    const int*   __restrict__ edge_src,
    const int*   __restrict__ batch,
    const ushort* __restrict__ qkv,
    const float* __restrict__ pool,
    float* __restrict__ out) {
  const int lane = threadIdx.x;            // channel
  const int wave = threadIdx.y;
  const int node = __builtin_amdgcn_readfirstlane(blockIdx.x * 4 + threadIdx.y);

  __shared__ int   sIdx[4][KMAX];
  __shared__ float sRel[4][3][KMAX];

  {
    int j = edge_src[(size_t)node * KMAX + lane];
    sIdx[wave][lane] = j;
    float px = pos[(size_t)node * 3 + 0];
    float py = pos[(size_t)node * 3 + 1];
    float pz = pos[(size_t)node * 3 + 2];
    sRel[wave][0][lane] = px - pos[(size_t)j * 3 + 0];
    sRel[wave][1][lane] = py - pos[(size_t)j * 3 + 1];
    sRel[wave][2][lane] = pz - pos[(size_t)j * 3 + 2];
  }
  __syncthreads();

  const float xi = x[(size_t)node * CH + lane];
  float res = 0.f;

#pragma unroll
  for (int dd = 0; dd < 3; ++dd) {
    const int dil = 1 << dd;
    const float q   = b2f(qkv[((size_t)dd * NP + node) * CH + lane]);
    const float wp0 = Wp[dd * 192 + 0 * CH + lane];
    const float wp1 = Wp[dd * 192 + 1 * CH + lane];
    const float wp2 = Wp[dd * 192 + 2 * CH + lane];
    const float bpv = bp[dd * CH + lane];
    const ushort* Kd = qkv + ((size_t)(3 + dd) * NP) * CH;
    const ushort* Vd = qkv + ((size_t)(6 + dd) * NP) * CH;

    float a[KNN], vd[KNN];
    float m = -INFINITY;
#pragma unroll
    for (int e = 0; e < KNN; ++e) {
      const int p = e * dil;
      int jj = __builtin_amdgcn_readfirstlane(sIdx[wave][p]);
      float r0 = sRel[wave][0][p];
      float r1 = sRel[wave][1][p];
      float r2 = sRel[wave][2][p];
      float delta = fmaf(r0, wp0, fmaf(r1, wp1, fmaf(r2, wp2, bpv)));
      float kv = b2f(Kd[(size_t)jj * CH + lane]);
      float vv = b2f(Vd[(size_t)jj * CH + lane]);
      a[e]  = q - kv + delta;
      vd[e] = vv + delta;
      m = fmaxf(m, a[e]);
    }
    float s = 0.f, acc = 0.f;
#pragma unroll
    for (int e = 0; e < KNN; ++e) {
      float w = __expf(a[e] - m);
      s += w;
      acc = fmaf(w, vd[e], acc);
    }
    float r = acc / (s + EPSF);
    res = (dd == 0) ? r : fmaxf(res, r);
  }

  const int b = batch[node];
  res = fmaxf(res, pool[b * CH + lane]);
  out[(size_t)node * CH + lane] = res + xi;
}

// ---------------------------------------------------------------------------
extern "C" void kernel_launch(void* const* d_in, const int* in_sizes, int n_in,
                              void* d_out, int out_size, void* d_ws, size_t ws_size,
                              hipStream_t stream) {
  const float* x    = (const float*)d_in[0];
  const float* pos  = (const float*)d_in[1];
  const float* Wv   = (const float*)d_in[2];
  const float* Wq   = (const float*)d_in[3];
  const float* Wk   = (const float*)d_in[4];
  const float* Wp   = (const float*)d_in[5];
  const float* bp   = (const float*)d_in[6];
  const int*   ei   = (const int*)d_in[7];
  const int*   batch = (const int*)d_in[8];
  float* out = (float*)d_out;

  char* wsb = (char*)d_ws;
  ushort* qkv   = (ushort*)wsb;
  ushort* x_bf  = (ushort*)(wsb + QKV_BYTES);
  ushort* wpack = (ushort*)(wsb + QKV_BYTES + XBF_BYTES);
  float*  pool  = (float*)(wsb + QKV_BYTES + XBF_BYTES + (size_t)WPACK_ELEMS * 2);

  // 0) convert x -> bf16, pack W into A-frag layout
  {
    int total = XV + WPACK_ELEMS;
    dim3 grid((total + 255) / 256);
    hipLaunchKernelGGL(convert_kernel, grid, dim3(256), 0, stream,
                       x, Wv, Wq, Wk, x_bf, wpack);
  }
  // 1) QKV projections via MFMA
  {
    dim3 grid((NTILES + 4 * TPW - 1) / (4 * TPW), 9);
    dim3 block(64, 4);
    hipLaunchKernelGGL(qkv_mfma, grid, block, 0, stream, x_bf, wpack, qkv);
  }
  // 2) per-cloud max pool
  {
    dim3 grid(NB);
    dim3 block(64, 4);
    hipLaunchKernelGGL(pool_kernel, grid, block, 0, stream, x, pool);
  }
  // 3) fused attention + combine
  {
    dim3 grid(NP / 4);
    dim3 block(64, 4);
    hipLaunchKernelGGL(attn_kernel, grid, block, 0, stream,
                       x, pos, Wp, bp, ei, batch, qkv, pool, out);
  }
}

// Round 3
// 225.902 us; speedup vs baseline: 1.3976x; 1.0337x over previous
//
#include <hip/hip_runtime.h>
#include <math.h>

#define NP 50000
#define CH 64
#define KMAX 64
#define KNN 16
#define NB 25
#define PTS (NP / NB)            // 2000
#define EPSF 1e-16f
#define NTILES (NP / 16)         // 3125 exact
#define TPW 4
#define L2E 1.4426950408889634f
#define LN2 0.6931471805599453f

typedef __attribute__((ext_vector_type(8))) short short8;
typedef __attribute__((ext_vector_type(4))) float float4v;
typedef __attribute__((ext_vector_type(4))) unsigned int uint4v;
typedef __attribute__((ext_vector_type(2))) unsigned int uint2v;
typedef __attribute__((ext_vector_type(4))) int int4v;
typedef __attribute__((ext_vector_type(4))) unsigned short ushort4v;

__device__ __forceinline__ ushort f2b(float f) {
  unsigned u = __float_as_uint(f);
  unsigned r = (u + 0x7FFFu + ((u >> 16) & 1u)) >> 16;
  return (ushort)r;
}
__device__ __forceinline__ float b2f(ushort h) {
  return __uint_as_float(((unsigned)h) << 16);
}

// ws layout (bytes):
//   qbf  : 3 * NP * CH * 2   (bf16, log2e-scaled Q)        = 19.2 MB
//   kvp  : 3 * NP * CH * 4   (packed: K_s bf16 hi | V lo)  = 38.4 MB
//   x_bf : NP * CH * 2                                     =  6.4 MB
//   wpack: 36864 ushort (A-frag layout; Q,K mats pre-scaled by log2e)
//   pool : NB * CH fp32
#define QBF_BYTES   ((size_t)3 * NP * CH * 2)
#define KVP_BYTES   ((size_t)3 * NP * CH * 4)
#define XBF_BYTES   ((size_t)NP * CH * 2)
#define WPACK_ELEMS (9 * 4 * 2 * 64 * 8)
#define XV (NP * CH / 4)         // 800000 float4 groups

// ---------------------------------------------------------------------------
// Kernel 0: prep = (blocks 0..24) per-cloud max pool  +  (rest) x->bf16 and
// W pack into A-frag layout. mats 0-2=Q (x log2e), 3-5=K (x log2e), 6-8=V.
//   wpack[((mat*4+mt)*2+ks)*512 + lane*8 + j]; oc=mt*16+(lane&15),
//   ic=ks*32+((lane>>4)&3)*8+j
// ---------------------------------------------------------------------------
__global__ __launch_bounds__(256) void prep_kernel(
    const float* __restrict__ x,
    const float* __restrict__ Wv,
    const float* __restrict__ Wq,
    const float* __restrict__ Wk,
    ushort* __restrict__ x_bf,
    ushort* __restrict__ wpack,
    float* __restrict__ pool) {
  const int tid = threadIdx.x;
  const int bid = blockIdx.x;
  __shared__ float red[4][CH];

  if (bid < NB) {                       // ---- pool path ----
    const int lane = tid & 63;
    const int wave = tid >> 6;
    const float* xb = x + (size_t)bid * PTS * CH;
    float m0 = -INFINITY, m1 = -INFINITY, m2 = -INFINITY, m3 = -INFINITY;
    for (int r = wave * 4; r < PTS; r += 16) {
      m0 = fmaxf(m0, xb[(size_t)(r + 0) * CH + lane]);
      m1 = fmaxf(m1, xb[(size_t)(r + 1) * CH + lane]);
      m2 = fmaxf(m2, xb[(size_t)(r + 2) * CH + lane]);
      m3 = fmaxf(m3, xb[(size_t)(r + 3) * CH + lane]);
    }
    red[wave][lane] = fmaxf(fmaxf(m0, m1), fmaxf(m2, m3));
    __syncthreads();
    if (wave == 0) {
      pool[bid * CH + lane] = fmaxf(fmaxf(red[0][lane], red[1][lane]),
                                    fmaxf(red[2][lane], red[3][lane]));
    }
  } else {                              // ---- convert / pack path ----
    const int gid = (bid - NB) * 256 + tid;
    if (gid < XV) {
      const float4* xv = (const float4*)x;
      float4 v = xv[gid];
      ushort4v o;
      o[0] = f2b(v.x); o[1] = f2b(v.y); o[2] = f2b(v.z); o[3] = f2b(v.w);
      *(ushort4v*)(x_bf + (size_t)gid * 4) = o;
    } else {
      int pid = gid - XV;
      if (pid < WPACK_ELEMS) {
        int j     = pid & 7;
        int lane  = (pid >> 3) & 63;
        int kstep = (pid >> 9) & 1;
        int mtile = (pid >> 10) & 3;
        int mat   = pid >> 12;
        const float* W;
        int d;
        float scale;
        if (mat < 3)      { W = Wq; d = mat;     scale = L2E; }
        else if (mat < 6) { W = Wk; d = mat - 3; scale = L2E; }
        else              { W = Wv; d = mat - 6; scale = 1.f; }
        int oc = mtile * 16 + (lane & 15);
        int ic = kstep * 32 + ((lane >> 4) & 3) * 8 + j;
        wpack[pid] = f2b(W[d * CH * CH + ic * CH + oc] * scale);
      }
    }
  }
}

// ---------------------------------------------------------------------------
// Kernel 1: projections via MFMA 16x16x32 bf16 (transposed: A=W^T, B=x^T).
// blockIdx.y: 0..2 = Q_dd (planar bf16), 3..8 = (dd,half) K&V packed dwords.
// D lane: node=lane&15, oc=mt*16+(lane>>4)*4+reg.
// ---------------------------------------------------------------------------
__global__ __launch_bounds__(256) void qkv_mfma(
    const ushort* __restrict__ x_bf,
    const ushort* __restrict__ wpack,
    ushort* __restrict__ qbf,
    unsigned int* __restrict__ kvp) {
  const int lane = threadIdx.x;
  const int wave = threadIdx.y;
  const int y    = blockIdx.y;
  const int kbase = (lane >> 4) * 8;
  const int tile0 = (blockIdx.x * 4 + wave) * TPW;

  if (y < 3) {                           // ---- Q slices ----
    short8 af[4][2];
#pragma unroll
    for (int mt = 0; mt < 4; ++mt)
#pragma unroll
      for (int ks = 0; ks < 2; ++ks)
        af[mt][ks] = *(const short8*)(wpack +
            ((((size_t)y * 4 + mt) * 2 + ks) * 64 + lane) * 8);
    ushort* outM = qbf + (size_t)y * NP * CH;
#pragma unroll
    for (int t = 0; t < TPW; ++t) {
      int tile = tile0 + t;
      if (tile >= NTILES) break;
      int myNode = tile * 16 + (lane & 15);
      const ushort* xr = x_bf + (size_t)myNode * CH;
      short8 b0 = *(const short8*)(xr + kbase);
      short8 b1 = *(const short8*)(xr + 32 + kbase);
#pragma unroll
      for (int mt = 0; mt < 4; ++mt) {
        float4v acc = {0.f, 0.f, 0.f, 0.f};
        acc = __builtin_amdgcn_mfma_f32_16x16x32_bf16(af[mt][0], b0, acc, 0, 0, 0);
        acc = __builtin_amdgcn_mfma_f32_16x16x32_bf16(af[mt][1], b1, acc, 0, 0, 0);
        int oc = mt * 16 + (lane >> 4) * 4;
        uint2v o;
        o[0] = (unsigned)f2b(acc[0]) | ((unsigned)f2b(acc[1]) << 16);
        o[1] = (unsigned)f2b(acc[2]) | ((unsigned)f2b(acc[3]) << 16);
        *(uint2v*)(outM + (size_t)myNode * CH + oc) = o;
      }
    }
  } else {                               // ---- KV packed slices ----
    const int k  = y - 3;
    const int dd = k >> 1;
    const int h  = k & 1;
    short8 afK[2][2], afV[2][2];
#pragma unroll
    for (int m2 = 0; m2 < 2; ++m2)
#pragma unroll
      for (int ks = 0; ks < 2; ++ks) {
        int mt = 2 * h + m2;
        afK[m2][ks] = *(const short8*)(wpack +
            ((((size_t)(3 + dd) * 4 + mt) * 2 + ks) * 64 + lane) * 8);
        afV[m2][ks] = *(const short8*)(wpack +
            ((((size_t)(6 + dd) * 4 + mt) * 2 + ks) * 64 + lane) * 8);
      }
    unsigned int* outKV = kvp + (size_t)dd * NP * CH;
#pragma unroll
    for (int t = 0; t < TPW; ++t) {
      int tile = tile0 + t;
      if (tile >= NTILES) break;
      int myNode = tile * 16 + (lane & 15);
      const ushort* xr = x_bf + (size_t)myNode * CH;
      short8 b0 = *(const short8*)(xr + kbase);
      short8 b1 = *(const short8*)(xr + 32 + kbase);
#pragma unroll
      for (int m2 = 0; m2 < 2; ++m2) {
        float4v aK = {0.f, 0.f, 0.f, 0.f};
        float4v aV = {0.f, 0.f, 0.f, 0.f};
        aK = __builtin_amdgcn_mfma_f32_16x16x32_bf16(afK[m2][0], b0, aK, 0, 0, 0);
        aK = __builtin_amdgcn_mfma_f32_16x16x32_bf16(afK[m2][1], b1, aK, 0, 0, 0);
        aV = __builtin_amdgcn_mfma_f32_16x16x32_bf16(afV[m2][0], b0, aV, 0, 0, 0);
        aV = __builtin_amdgcn_mfma_f32_16x16x32_bf16(afV[m2][1], b1, aV, 0, 0, 0);
        int oc = (2 * h + m2) * 16 + (lane >> 4) * 4;
        uint4v o;
#pragma unroll
        for (int i = 0; i < 4; ++i)
          o[i] = ((unsigned)f2b(aK[i]) << 16) | (unsigned)f2b(aV[i]);
        *(uint4v*)(outKV + (size_t)myNode * CH + oc) = o;
      }
    }
  }
}

// ---------------------------------------------------------------------------
// Kernel 2: fused attention. Block = 16 nodes; wave = 4 nodes; lane: node
// group g=lane>>4, channels (lane&15)*4..+3 (float4). Single-pass softmax in
// log2 domain (no max subtraction: |a| << 88). One ds_read_b128 (rel+rowOfs)
// + one global_load_dwordx4 (packed KV) per edge-slot.
// ---------------------------------------------------------------------------
__global__ __launch_bounds__(256) void attn_kernel(
    const float* __restrict__ x,
    const float* __restrict__ pos,
    const float* __restrict__ Wp,
    const float* __restrict__ bp,
    const int*   __restrict__ edge_src,
    const ushort* __restrict__ qbf,
    const unsigned int* __restrict__ kvp,
    const float* __restrict__ pool,
    float* __restrict__ out) {
  const int tid = threadIdx.y * 64 + threadIdx.x;
  __shared__ float sEdge[16 * KMAX * 4];   // {relx,rely,relz,rowByteOfs} x 64 x 16

  {                                        // ---- cooperative prologue ----
    const int nl = tid >> 4;               // node-local 0..15
    const int p0 = (tid & 15) * 4;
    const int nd = blockIdx.x * 16 + nl;
    int4v jj = *(const int4v*)(edge_src + (size_t)nd * KMAX + p0);
    float px = pos[nd * 3 + 0];
    float py = pos[nd * 3 + 1];
    float pz = pos[nd * 3 + 2];
#pragma unroll
    for (int u = 0; u < 4; ++u) {
      int j = jj[u];
      float4v w;
      w[0] = px - pos[j * 3 + 0];
      w[1] = py - pos[j * 3 + 1];
      w[2] = pz - pos[j * 3 + 2];
      w[3] = __int_as_float(j << 8);       // byte offset of packed-KV row
      *(float4v*)&sEdge[(nl * KMAX + p0 + u) * 4] = w;
    }
  }
  __syncthreads();

  const int lane = threadIdx.x;
  const int g  = lane >> 4;
  const int cl = lane & 15;
  const int nodeSlot = threadIdx.y * 4 + g;
  const int node = blockIdx.x * 16 + nodeSlot;
  const float* sMy = &sEdge[nodeSlot * KMAX * 4];
  const unsigned clOfs = (unsigned)(cl << 4);

  float4v res = {0.f, 0.f, 0.f, 0.f};

#pragma unroll
  for (int dd = 0; dd < 3; ++dd) {
    float4v q, wp0, wp1, wp2, bq;
    {
      ushort4v qh = *(const ushort4v*)(qbf + ((size_t)dd * NP + node) * CH + cl * 4);
#pragma unroll
      for (int i = 0; i < 4; ++i) q[i] = b2f(qh[i]);
      const float* WpD = Wp + dd * 192;
      wp0 = *(const float4v*)(WpD + 0 * 64 + cl * 4) * L2E;
      wp1 = *(const float4v*)(WpD + 1 * 64 + cl * 4) * L2E;
      wp2 = *(const float4v*)(WpD + 2 * 64 + cl * 4) * L2E;
      float4v bpv = *(const float4v*)(bp + dd * 64 + cl * 4);
      bq = q + bpv * L2E;                  // q_s + bp_s
    }
    const char* KVb = (const char*)(kvp + (size_t)dd * NP * CH);
    const int dil = 1 << dd;

    float4v s    = {0.f, 0.f, 0.f, 0.f};
    float4v accv = {0.f, 0.f, 0.f, 0.f};
    float4v accd = {0.f, 0.f, 0.f, 0.f};
#pragma unroll
    for (int e = 0; e < KNN; ++e) {
      const int p = e * dil;
      float4v w = *(const float4v*)(sMy + p * 4);
      unsigned ofs = __float_as_uint(w[3]) + clOfs;
      uint4v u = *(const uint4v*)(KVb + ofs);
      float4v kf, vf, wgt;
#pragma unroll
      for (int i = 0; i < 4; ++i) kf[i] = __uint_as_float(u[i] & 0xFFFF0000u);
#pragma unroll
      for (int i = 0; i < 4; ++i) vf[i] = __uint_as_float(u[i] << 16);
      float4v t = bq + w[0] * wp0 + w[1] * wp1 + w[2] * wp2;  // q_s + delta_s
      float4v a = t - kf;                  // log2-domain score
#pragma unroll
      for (int i = 0; i < 4; ++i) wgt[i] = __builtin_amdgcn_exp2f(a[i]);
      s    += wgt;
      accv += wgt * vf;
      float4v dlt = t - q;                 // delta_s
      accd += wgt * dlt;
    }
    float4v r;
#pragma unroll
    for (int i = 0; i < 4; ++i)
      r[i] = (accv[i] + LN2 * accd[i]) * __builtin_amdgcn_rcpf(s[i] + EPSF);
    if (dd == 0) {
      res = r;
    } else {
#pragma unroll
      for (int i = 0; i < 4; ++i) res[i] = fmaxf(res[i], r[i]);
    }
  }

  const int b = node / PTS;
  float4v pv = *(const float4v*)(pool + b * CH + cl * 4);
  float4v xv = *(const float4v*)(x + (size_t)node * CH + cl * 4);
#pragma unroll
  for (int i = 0; i < 4; ++i) res[i] = fmaxf(res[i], pv[i]) + xv[i];
  *(float4v*)(out + (size_t)node * CH + cl * 4) = res;
}

// ---------------------------------------------------------------------------
extern "C" void kernel_launch(void* const* d_in, const int* in_sizes, int n_in,
                              void* d_out, int out_size, void* d_ws, size_t ws_size,
                              hipStream_t stream) {
  const float* x    = (const float*)d_in[0];
  const float* pos  = (const float*)d_in[1];
  const float* Wv   = (const float*)d_in[2];
  const float* Wq   = (const float*)d_in[3];
  const float* Wk   = (const float*)d_in[4];
  const float* Wp   = (const float*)d_in[5];
  const float* bp   = (const float*)d_in[6];
  const int*   ei   = (const int*)d_in[7];
  float* out = (float*)d_out;

  char* wsb = (char*)d_ws;
  ushort* qbf   = (ushort*)wsb;
  unsigned int* kvp = (unsigned int*)(wsb + QBF_BYTES);
  ushort* x_bf  = (ushort*)(wsb + QBF_BYTES + KVP_BYTES);
  ushort* wpack = (ushort*)(wsb + QBF_BYTES + KVP_BYTES + XBF_BYTES);
  float*  pool  = (float*)(wsb + QBF_BYTES + KVP_BYTES + XBF_BYTES +
                           (size_t)WPACK_ELEMS * 2);

  // 0) pool + convert + pack
  {
    int convBlocks = (XV + WPACK_ELEMS + 255) / 256;
    dim3 grid(NB + convBlocks);
    hipLaunchKernelGGL(prep_kernel, grid, dim3(256), 0, stream,
                       x, Wv, Wq, Wk, x_bf, wpack, pool);
  }
  // 1) Q (planar bf16) + packed KV via MFMA
  {
    dim3 grid((NTILES + 4 * TPW - 1) / (4 * TPW), 9);
    dim3 block(64, 4);
    hipLaunchKernelGGL(qkv_mfma, grid, block, 0, stream, x_bf, wpack, qbf, kvp);
  }
  // 2) fused attention + combine
  {
    dim3 grid(NP / 16);
    dim3 block(64, 4);
    hipLaunchKernelGGL(attn_kernel, grid, block, 0, stream,
                       x, pos, Wp, bp, ei, qbf, kvp, pool, out);
  }
}